// Round 1
// baseline (22.847 us; speedup 1.0000x reference)
//
#include <hip/hip_runtime.h>

#define NB 256

// Closed-form first column of the real Wigner-D blocks, ell = 0..3.
// Basis/ordering matches the reference's _real_sh. Only columns 0 and 1 of R
// (entries a,b,d,e,g,h) appear in the result.
__global__ __launch_bounds__(NB) void rot_embed_kernel(const float* __restrict__ R,
                                                       float* __restrict__ out,
                                                       int n) {
    __shared__ float s[NB * 9];
    const int t = threadIdx.x;
    const long long base  = (long long)blockIdx.x * NB;
    const long long ebase = base * 9;
    const long long total = (long long)n * 9;
#pragma unroll
    for (int k = 0; k < 9; ++k) {
        long long idx = ebase + (long long)k * NB + t;
        if (idx < total) s[k * NB + t] = R[idx];
    }
    __syncthreads();
    const long long row = base + t;
    if (row >= n) return;

    const float* m = &s[t * 9];          // stride 9 -> bank-conflict-free
    const float a = m[0], b = m[1];      // R row0
    const float d = m[3], e = m[4];      // R row1
    const float g = m[6], h = m[7];      // R row2

    const float ab = a * b, de = d * e, gh = g * h;
    const float a2 = a * a, b2 = b * b, d2 = d * d;
    const float e2 = e * e, g2 = g * g, h2 = h * h;

    // ell = 2
    const float t4 = a * e + b * d;
    const float t5 = d * h + e * g;
    const float t6 = 0.5773502691896258f * (2.0f * gh - ab - de);
    const float t7 = a * h + b * g;
    const float t8 = ab - de;

    // ell = 3
    const float t9  = 0.25f * (3.0f * a2 * e + 6.0f * ab * d - 3.0f * d2 * e
                               - 3.0f * b2 * e + e2 * e);
    const float t10 = 1.2247448713915890f * (a * t5 + b * (d * g - e * h));
    const float t11 = 0.1936491673103709f * (4.0f * g2 * e + 8.0f * gh * d - a2 * e
                                             - 2.0f * ab * d - 3.0f * d2 * e
                                             - 4.0f * h2 * e + b2 * e + e2 * e);
    const float t12 = 0.1581138830084190f * (6.0f * g2 * h - 3.0f * a2 * h - 6.0f * ab * g
                                             - 3.0f * d2 * h - 6.0f * de * g - 2.0f * h2 * h
                                             + 3.0f * b2 * h + 3.0f * e2 * h);
    const float t13 = 0.1936491673103709f * (4.0f * g2 * b + 8.0f * gh * a - 3.0f * a2 * b
                                             - d2 * b - 2.0f * de * a - 4.0f * h2 * b
                                             + b2 * b + e2 * b);
    const float t14 = 0.6123724356957945f * (a2 * h + 2.0f * ab * g - d2 * h
                                             - 2.0f * de * g - b2 * h + e2 * h);
    const float t15 = 0.25f * (3.0f * a2 * b - 3.0f * d2 * b - 6.0f * de * a
                               - b2 * b + 3.0f * e2 * b);

    float4* op = (float4*)(out + row * 16);  // 64B-aligned per row
    op[0] = make_float4(1.0f, e, h, b);      // ell=0, ell=1 (y,z,x ordering)
    op[1] = make_float4(t4, t5, t6, t7);
    op[2] = make_float4(t8, t9, t10, t11);
    op[3] = make_float4(t12, t13, t14, t15);
}

extern "C" void kernel_launch(void* const* d_in, const int* in_sizes, int n_in,
                              void* d_out, int out_size, void* d_ws, size_t ws_size,
                              hipStream_t stream) {
    const float* R = (const float*)d_in[0];
    float* out = (float*)d_out;
    const int n = in_sizes[0] / 9;           // 500000 rotation matrices
    const int blocks = (n + NB - 1) / NB;
    rot_embed_kernel<<<blocks, NB, 0, stream>>>(R, out, n);
}

// Round 2
// 15.862 us; speedup vs baseline: 1.4404x; 1.4404x over previous
//
#include <hip/hip_runtime.h>

#define NB 256
#define ROWS (NB / 4)   // 64 rotations per block; 4 lanes cooperate per rotation

// Closed-form first column of the real Wigner-D blocks, ell = 0..3.
// Each 4-lane group computes one rotation's 16 outputs redundantly; lane q of
// the group stores the q-th float4 quarter -> per-instruction stores are fully
// coalesced (contiguous 16 B/lane across the wave).
__global__ __launch_bounds__(NB) void rot_embed_kernel(const float* __restrict__ R,
                                                       float* __restrict__ out,
                                                       int n) {
    __shared__ float s[ROWS * 9];        // 576 floats
    const int t = threadIdx.x;
    const long long base  = (long long)blockIdx.x * ROWS;
    const long long ebase = base * 9;
    const long long total = (long long)n * 9;
#pragma unroll
    for (int k = 0; k < 3; ++k) {
        const int li = k * NB + t;
        if (li < ROWS * 9) {
            const long long gi = ebase + li;
            if (gi < total) s[li] = R[gi];
        }
    }
    __syncthreads();

    const int r = t >> 2;                // rotation within block
    const int q = t & 3;                 // which float4 quarter this lane stores
    const long long row = base + r;
    if (row >= n) return;

    const float* m = &s[r * 9];          // 4 lanes same address -> LDS broadcast
    const float a = m[0], b = m[1];      // R row0
    const float d = m[3], e = m[4];      // R row1
    const float g = m[6], h = m[7];      // R row2

    const float ab = a * b, de = d * e, gh = g * h;
    const float a2 = a * a, b2 = b * b, d2 = d * d;
    const float e2 = e * e, g2 = g * g, h2 = h * h;

    // ell = 2
    const float t4 = a * e + b * d;
    const float t5 = d * h + e * g;
    const float t6 = 0.5773502691896258f * (2.0f * gh - ab - de);
    const float t7 = a * h + b * g;
    const float t8 = ab - de;

    // ell = 3
    const float t9  = 0.25f * (3.0f * a2 * e + 6.0f * ab * d - 3.0f * d2 * e
                               - 3.0f * b2 * e + e2 * e);
    const float t10 = 1.2247448713915890f * (a * t5 + b * (d * g - e * h));
    const float t11 = 0.1936491673103709f * (4.0f * g2 * e + 8.0f * gh * d - a2 * e
                                             - 2.0f * ab * d - 3.0f * d2 * e
                                             - 4.0f * h2 * e + b2 * e + e2 * e);
    const float t12 = 0.1581138830084190f * (6.0f * g2 * h - 3.0f * a2 * h - 6.0f * ab * g
                                             - 3.0f * d2 * h - 6.0f * de * g - 2.0f * h2 * h
                                             + 3.0f * b2 * h + 3.0f * e2 * h);
    const float t13 = 0.1936491673103709f * (4.0f * g2 * b + 8.0f * gh * a - 3.0f * a2 * b
                                             - d2 * b - 2.0f * de * a - 4.0f * h2 * b
                                             + b2 * b + e2 * b);
    const float t14 = 0.6123724356957945f * (a2 * h + 2.0f * ab * g - d2 * h
                                             - 2.0f * de * g - b2 * h + e2 * h);
    const float t15 = 0.25f * (3.0f * a2 * b - 3.0f * d2 * b - 6.0f * de * a
                               - b2 * b + 3.0f * e2 * b);

    // Branchless quarter select (scalar cndmask chains; no divergence).
    const float vx = (q == 0) ? 1.0f : (q == 1) ? t4  : (q == 2) ? t8  : t12;
    const float vy = (q == 0) ? e    : (q == 1) ? t5  : (q == 2) ? t9  : t13;
    const float vz = (q == 0) ? h    : (q == 1) ? t6  : (q == 2) ? t10 : t14;
    const float vw = (q == 0) ? b    : (q == 1) ? t7  : (q == 2) ? t11 : t15;

    // float4 index = row*4 + q = base*4 + t  -> contiguous across the wave.
    ((float4*)out)[base * 4 + t] = make_float4(vx, vy, vz, vw);
}

extern "C" void kernel_launch(void* const* d_in, const int* in_sizes, int n_in,
                              void* d_out, int out_size, void* d_ws, size_t ws_size,
                              hipStream_t stream) {
    const float* R = (const float*)d_in[0];
    float* out = (float*)d_out;
    const int n = in_sizes[0] / 9;               // 500000 rotation matrices
    const int blocks = (n + ROWS - 1) / ROWS;    // 7813 blocks
    rot_embed_kernel<<<blocks, NB, 0, stream>>>(R, out, n);
}

// Round 4
// 14.852 us; speedup vs baseline: 1.5384x; 1.0680x over previous
//
#include <hip/hip_runtime.h>

#define NB 256
#define TILE 256                 // rotations per block
#define PASSES 4                 // TILE / (NB/4)

typedef float vfloat4 __attribute__((ext_vector_type(4)));  // clang vector: OK for nontemporal builtins

// Closed-form first column of the real Wigner-D blocks, ell = 0..3.
// Per block: stage TILE*9 floats to LDS with coalesced float4 loads, then 4
// passes where each 4-lane group computes one rotation redundantly and lane q
// stores the q-th float4 quarter (contiguous 16 B/lane across the wave).
__global__ __launch_bounds__(NB) void rot_embed_kernel(const float* __restrict__ R,
                                                       float* __restrict__ out,
                                                       int n) {
    __shared__ float s[TILE * 9];            // 9216 B
    const int t = threadIdx.x;
    const long long base = (long long)blockIdx.x * TILE;

    // Stage: 576 float4s, contiguous. n*9 is divisible by 4 (500000*9 = 4.5e6).
    {
        const vfloat4* Rv = (const vfloat4*)R;
        const long long base4  = base * 9 / 4;           // block's first float4
        const long long total4 = (long long)n * 9 / 4;
        vfloat4* sv = (vfloat4*)s;
#pragma unroll
        for (int k = 0; k < 3; ++k) {
            const int li = k * NB + t;
            if (li < TILE * 9 / 4) {
                const long long gi = base4 + li;
                if (gi < total4) sv[li] = Rv[gi];
            }
        }
    }
    __syncthreads();

    const int q = t & 3;                     // which float4 quarter this lane stores
#pragma unroll
    for (int p = 0; p < PASSES; ++p) {
        const int rloc = p * (NB / 4) + (t >> 2);
        const long long row = base + rloc;
        if (row >= n) break;

        const float* m = &s[rloc * 9];       // 4 lanes same addr -> LDS broadcast
        const float a = m[0], b = m[1];      // R row0
        const float d = m[3], e = m[4];      // R row1
        const float g = m[6], h = m[7];      // R row2

        const float ab = a * b, de = d * e, gh = g * h;
        const float a2 = a * a, b2 = b * b, d2 = d * d;
        const float e2 = e * e, g2 = g * g, h2 = h * h;

        // ell = 2
        const float t4 = a * e + b * d;
        const float t5 = d * h + e * g;
        const float t6 = 0.5773502691896258f * (2.0f * gh - ab - de);
        const float t7 = a * h + b * g;
        const float t8 = ab - de;

        // ell = 3
        const float t9  = 0.25f * (3.0f * a2 * e + 6.0f * ab * d - 3.0f * d2 * e
                                   - 3.0f * b2 * e + e2 * e);
        const float t10 = 1.2247448713915890f * (a * t5 + b * (d * g - e * h));
        const float t11 = 0.1936491673103709f * (4.0f * g2 * e + 8.0f * gh * d - a2 * e
                                                 - 2.0f * ab * d - 3.0f * d2 * e
                                                 - 4.0f * h2 * e + b2 * e + e2 * e);
        const float t12 = 0.1581138830084190f * (6.0f * g2 * h - 3.0f * a2 * h - 6.0f * ab * g
                                                 - 3.0f * d2 * h - 6.0f * de * g - 2.0f * h2 * h
                                                 + 3.0f * b2 * h + 3.0f * e2 * h);
        const float t13 = 0.1936491673103709f * (4.0f * g2 * b + 8.0f * gh * a - 3.0f * a2 * b
                                                 - d2 * b - 2.0f * de * a - 4.0f * h2 * b
                                                 + b2 * b + e2 * b);
        const float t14 = 0.6123724356957945f * (a2 * h + 2.0f * ab * g - d2 * h
                                                 - 2.0f * de * g - b2 * h + e2 * h);
        const float t15 = 0.25f * (3.0f * a2 * b - 3.0f * d2 * b - 6.0f * de * a
                                   - b2 * b + 3.0f * e2 * b);

        // Branchless quarter select (no divergence within the 4-lane group).
        const float vx = (q == 0) ? 1.0f : (q == 1) ? t4  : (q == 2) ? t8  : t12;
        const float vy = (q == 0) ? e    : (q == 1) ? t5  : (q == 2) ? t9  : t13;
        const float vz = (q == 0) ? h    : (q == 1) ? t6  : (q == 2) ? t10 : t14;
        const float vw = (q == 0) ? b    : (q == 1) ? t7  : (q == 2) ? t11 : t15;

        // float4 index = row*4 + q = base*4 + p*NB + t -> contiguous per pass.
        vfloat4 v = {vx, vy, vz, vw};
        __builtin_nontemporal_store(v, (vfloat4*)out + (base * 4 + p * NB + t));
    }
}

extern "C" void kernel_launch(void* const* d_in, const int* in_sizes, int n_in,
                              void* d_out, int out_size, void* d_ws, size_t ws_size,
                              hipStream_t stream) {
    const float* R = (const float*)d_in[0];
    float* out = (float*)d_out;
    const int n = in_sizes[0] / 9;                 // 500000 rotation matrices
    const int blocks = (n + TILE - 1) / TILE;      // 1954 blocks
    rot_embed_kernel<<<blocks, NB, 0, stream>>>(R, out, n);
}

// Round 5
// 13.639 us; speedup vs baseline: 1.6751x; 1.0889x over previous
//
#include <hip/hip_runtime.h>

#define NB 256

typedef float vfloat4 __attribute__((ext_vector_type(4)));

// Quad-perm broadcast within each 4-lane group (ds_swizzle, bit15=1 mode).
// PAT = 0x8000 | s | s<<2 | s<<4 | s<<6 broadcasts lane s of the quad.
template <int PAT>
__device__ __forceinline__ float qbcast(float v) {
    return __int_as_float(__builtin_amdgcn_ds_swizzle(__float_as_int(v), PAT));
}

// Closed-form first column of the real Wigner-D blocks, ell = 0..3.
// Fully streaming: no LDS tile, no barrier. Each 4-lane quad owns one rotation;
// lane q loads m[q] and m[q+4] (coalesced dwords), quad-perm swizzles
// distribute {a,b,d,e,g,h}; every lane computes the polynomials and stores its
// float4 quarter at out[tid] -> contiguous nontemporal dwordx4 stores.
__global__ __launch_bounds__(NB) void rot_embed_kernel(const float* __restrict__ R,
                                                       float* __restrict__ out,
                                                       int n) {
    const long long tid = (long long)blockIdx.x * NB + threadIdx.x;
    const long long row = tid >> 2;              // rotation index
    if (row >= n) return;
    const int q = threadIdx.x & 3;               // quarter owned by this lane

    const float* rp = R + row * 9;
    const float v0 = rp[q];                      // m[q]
    const float v1 = rp[q + 4];                  // m[q+4]

    // Distribute the 6 needed entries of R (cols 0,1) across the quad.
    const float a = qbcast<0x8000>(v0);          // m[0] from lane 0
    const float b = qbcast<0x8055>(v0);          // m[1] from lane 1
    const float d = qbcast<0x80FF>(v0);          // m[3] from lane 3
    const float e = qbcast<0x8000>(v1);          // m[4] from lane 0
    const float g = qbcast<0x80AA>(v1);          // m[6] from lane 2
    const float h = qbcast<0x80FF>(v1);          // m[7] from lane 3

    const float ab = a * b, de = d * e, gh = g * h;
    const float a2 = a * a, b2 = b * b, d2 = d * d;
    const float e2 = e * e, g2 = g * g, h2 = h * h;

    // ell = 2
    const float t4 = a * e + b * d;
    const float t5 = d * h + e * g;
    const float t6 = 0.5773502691896258f * (2.0f * gh - ab - de);
    const float t7 = a * h + b * g;
    const float t8 = ab - de;

    // ell = 3
    const float t9  = 0.25f * (3.0f * a2 * e + 6.0f * ab * d - 3.0f * d2 * e
                               - 3.0f * b2 * e + e2 * e);
    const float t10 = 1.2247448713915890f * (a * t5 + b * (d * g - e * h));
    const float t11 = 0.1936491673103709f * (4.0f * g2 * e + 8.0f * gh * d - a2 * e
                                             - 2.0f * ab * d - 3.0f * d2 * e
                                             - 4.0f * h2 * e + b2 * e + e2 * e);
    const float t12 = 0.1581138830084190f * (6.0f * g2 * h - 3.0f * a2 * h - 6.0f * ab * g
                                             - 3.0f * d2 * h - 6.0f * de * g - 2.0f * h2 * h
                                             + 3.0f * b2 * h + 3.0f * e2 * h);
    const float t13 = 0.1936491673103709f * (4.0f * g2 * b + 8.0f * gh * a - 3.0f * a2 * b
                                             - d2 * b - 2.0f * de * a - 4.0f * h2 * b
                                             + b2 * b + e2 * b);
    const float t14 = 0.6123724356957945f * (a2 * h + 2.0f * ab * g - d2 * h
                                             - 2.0f * de * g - b2 * h + e2 * h);
    const float t15 = 0.25f * (3.0f * a2 * b - 3.0f * d2 * b - 6.0f * de * a
                               - b2 * b + 3.0f * e2 * b);

    // Branchless quarter select (no divergence within the quad).
    const float vx = (q == 0) ? 1.0f : (q == 1) ? t4  : (q == 2) ? t8  : t12;
    const float vy = (q == 0) ? e    : (q == 1) ? t5  : (q == 2) ? t9  : t13;
    const float vz = (q == 0) ? h    : (q == 1) ? t6  : (q == 2) ? t10 : t14;
    const float vw = (q == 0) ? b    : (q == 1) ? t7  : (q == 2) ? t11 : t15;

    vfloat4 v = {vx, vy, vz, vw};
    __builtin_nontemporal_store(v, (vfloat4*)out + tid);   // addr = tid*16B, contiguous
}

extern "C" void kernel_launch(void* const* d_in, const int* in_sizes, int n_in,
                              void* d_out, int out_size, void* d_ws, size_t ws_size,
                              hipStream_t stream) {
    const float* R = (const float*)d_in[0];
    float* out = (float*)d_out;
    const int n = in_sizes[0] / 9;                       // 500000 rotation matrices
    const long long threads = (long long)n * 4;          // one float4 per thread
    const int blocks = (int)((threads + NB - 1) / NB);   // 7813 blocks
    rot_embed_kernel<<<blocks, NB, 0, stream>>>(R, out, n);
}